// Round 3
// baseline (491.487 us; speedup 1.0000x reference)
//
#include <hip/hip_runtime.h>

typedef short bf16x8 __attribute__((ext_vector_type(8)));
typedef float f32x4 __attribute__((ext_vector_type(4)));

__device__ __forceinline__ float b2f(unsigned short u) {
  union { unsigned int i; float f; } v; v.i = ((unsigned int)u) << 16; return v.f;
}
__device__ __forceinline__ unsigned short f2b(float f) {
  unsigned int u = __float_as_uint(f);
  u += 0x7fffu + ((u >> 16) & 1u);
  return (unsigned short)(u >> 16);
}
__device__ __forceinline__ float silu_f(float s) { return s / (1.0f + __expf(-s)); }

// split fp32 -> (hi, lo) bf16
__device__ __forceinline__ void split2(float f, unsigned short& h, unsigned short& l) {
  h = f2b(f);
  l = f2b(f - b2f(h));
}
__device__ __forceinline__ void cvt8(const float* p, bf16x8& hi, bf16x8& lo) {
  float4 a = *(const float4*)(p);
  float4 b = *(const float4*)(p + 4);
  float v[8] = {a.x, a.y, a.z, a.w, b.x, b.y, b.z, b.w};
  #pragma unroll
  for (int j = 0; j < 8; j++) {
    unsigned short h, l; split2(v[j], h, l);
    hi[j] = (short)h; lo[j] = (short)l;
  }
}

// K1: T = silu(x + pab) + pqb, stored as packed (hi | lo<<16) u32 -> out[:,256:512]
__global__ __launch_bounds__(256) void k_prep(
    const float* __restrict__ x, const float* __restrict__ pab,
    const float* __restrict__ pqb, float* __restrict__ out) {
  long long e = ((long long)blockIdx.x * 256 + threadIdx.x) * 4;
  int b = (int)(e >> 20);
  int c = ((int)(e >> 12)) & 255;
  int n = (int)(e & 4095);
  float4 xv = *(const float4*)(x + e);
  float pa = pab[c], pq = pqb[c];
  float tv[4] = {silu_f(xv.x + pa) + pq, silu_f(xv.y + pa) + pq,
                 silu_f(xv.z + pa) + pq, silu_f(xv.w + pa) + pq};
  uint4 o;
  unsigned int* po = (unsigned int*)&o;
  #pragma unroll
  for (int i = 0; i < 4; i++) {
    unsigned short h, l; split2(tv[i], h, l);
    po[i] = (unsigned int)h | ((unsigned int)l << 16);
  }
  unsigned int* To = (unsigned int*)out;
  *(uint4*)(To + ((long long)(b * 512 + 256 + c)) * 4096 + n) = o;
}

// K6 (last): x_preact = silu(x + pab) fp32 -> out[:,0:256]
__global__ __launch_bounds__(256) void k_act(
    const float* __restrict__ x, const float* __restrict__ pab,
    float* __restrict__ out) {
  long long e = ((long long)blockIdx.x * 256 + threadIdx.x) * 4;
  int b = (int)(e >> 20);
  int c = ((int)(e >> 12)) & 255;
  int n = (int)(e & 4095);
  float4 xv = *(const float4*)(x + e);
  float pa = pab[c];
  float4 o = {silu_f(xv.x + pa), silu_f(xv.y + pa), silu_f(xv.z + pa), silu_f(xv.w + pa)};
  *(float4*)(out + ((long long)(b * 512 + c)) * 4096 + n) = o;
}

// K2/K4: GEMM qkv rows [o_base, o_base+obt*128). use_lo=1 -> 3-term split-bf16.
//   part 0 (q): +bias+PE, FiLM -> out[:,0:256] fp32
//   part 1 (k): +bias+PE      -> kv fp32
//   part 2 (v): +bias         -> kv fp32 (after k consumed)
__global__ __launch_bounds__(256) void k_qkv(
    const float* __restrict__ Wq, const float* __restrict__ qkvb,
    const float* __restrict__ peqh, const float* __restrict__ peqw,
    const float* __restrict__ pekh, const float* __restrict__ pekw,
    const float* __restrict__ modm, const float* __restrict__ modb,
    float* __restrict__ out, float* __restrict__ kv,
    int o_base, int obt, int use_lo) {
  __shared__ __align__(16) unsigned short As_h[128 * 64], As_l[128 * 64];
  __shared__ __align__(16) unsigned short Bs_h[128 * 64], Bs_l[128 * 64];
  int bx = blockIdx.x;
  int nb = bx & 31;
  int hb = bx >> 5;
  int ob = hb % obt;
  int b  = hb / obt;
  int o0 = o_base + ob * 128, n0 = nb * 128;
  int t = threadIdx.x;
  int lane = t & 63, w = t >> 6;
  int wm = w >> 1, wn = w & 1;
  int l15 = lane & 15, l4 = lane >> 4;
  const unsigned int* Tb = (const unsigned int*)out + ((long long)(b * 512 + 256)) * 4096;

  f32x4 z = {0.f, 0.f, 0.f, 0.f};
  f32x4 acc[4][4];
  #pragma unroll
  for (int i = 0; i < 4; i++)
    #pragma unroll
    for (int j = 0; j < 4; j++) acc[i][j] = z;

  for (int k0 = 0; k0 < 256; k0 += 64) {
    // A stage: W fp32 -> hi/lo bf16
    #pragma unroll
    for (int p = 0; p < 8; p++) {
      int chunk = t + p * 256;
      int ao = chunk >> 4, am = (chunk & 15) * 4;
      float4 wv = *(const float4*)(Wq + (o0 + ao) * 256 + k0 + am);
      float v[4] = {wv.x, wv.y, wv.z, wv.w};
      unsigned short h[4], l[4];
      #pragma unroll
      for (int j = 0; j < 4; j++) split2(v[j], h[j], l[j]);
      uint2 ph; ph.x = (unsigned int)h[0] | ((unsigned int)h[1] << 16);
      ph.y = (unsigned int)h[2] | ((unsigned int)h[3] << 16);
      *(uint2*)(As_h + ao * 64 + am) = ph;
      if (use_lo) {
        uint2 pl; pl.x = (unsigned int)l[0] | ((unsigned int)l[1] << 16);
        pl.y = (unsigned int)l[2] | ((unsigned int)l[3] << 16);
        *(uint2*)(As_l + ao * 64 + am) = pl;
      }
    }
    // B stage: packed T (hi|lo) -> transposed [n][c] planes
    int cc = t & 63;
    int nch = t >> 6;
    #pragma unroll
    for (int p = 0; p < 8; p++) {
      int nloc = p * 16 + nch * 4;
      uint4 tv = *(const uint4*)(Tb + (long long)(k0 + cc) * 4096 + n0 + nloc);
      unsigned int uu[4] = {tv.x, tv.y, tv.z, tv.w};
      #pragma unroll
      for (int j = 0; j < 4; j++) {
        Bs_h[(nloc + j) * 64 + cc] = (unsigned short)(uu[j] & 0xffffu);
        if (use_lo) Bs_l[(nloc + j) * 64 + cc] = (unsigned short)(uu[j] >> 16);
      }
    }
    __syncthreads();
    #pragma unroll
    for (int ks = 0; ks < 2; ks++) {
      bf16x8 ah[4], bh[4], al[4], bl[4];
      #pragma unroll
      for (int i = 0; i < 4; i++) {
        int arow = (wm * 64 + i * 16 + l15) * 64 + ks * 32 + l4 * 8;
        int brow = (wn * 64 + i * 16 + l15) * 64 + ks * 32 + l4 * 8;
        ah[i] = *(const bf16x8*)(As_h + arow);
        bh[i] = *(const bf16x8*)(Bs_h + brow);
        if (use_lo) {
          al[i] = *(const bf16x8*)(As_l + arow);
          bl[i] = *(const bf16x8*)(Bs_l + brow);
        }
      }
      #pragma unroll
      for (int i = 0; i < 4; i++)
        #pragma unroll
        for (int j = 0; j < 4; j++) {
          acc[i][j] = __builtin_amdgcn_mfma_f32_16x16x32_bf16(ah[i], bh[j], acc[i][j], 0, 0, 0);
          if (use_lo) {
            acc[i][j] = __builtin_amdgcn_mfma_f32_16x16x32_bf16(ah[i], bl[j], acc[i][j], 0, 0, 0);
            acc[i][j] = __builtin_amdgcn_mfma_f32_16x16x32_bf16(al[i], bh[j], acc[i][j], 0, 0, 0);
          }
        }
    }
    __syncthreads();
  }

  int part = o0 >> 8;
  #pragma unroll
  for (int i = 0; i < 4; i++) {
    #pragma unroll
    for (int r = 0; r < 4; r++) {
      int o = o0 + wm * 64 + i * 16 + l4 * 4 + r;
      int cch = o & 255;
      float bias = qkvb[o];
      float mm = 0.f, mb = 0.f;
      if (part == 0) { mm = modm[b * 256 + cch]; mb = modb[b * 256 + cch]; }
      #pragma unroll
      for (int j = 0; j < 4; j++) {
        int n = n0 + wn * 64 + j * 16 + l15;
        float v = acc[i][j][r] + bias;
        int hh = n >> 6, ww = n & 63;
        if (part == 0) {
          v += peqh[cch * 64 + hh] + peqw[cch * 64 + ww];
          v = v * mm + mb;
          out[((long long)(b * 512 + cch)) * 4096 + n] = v;
        } else {
          if (part == 1) v += pekh[cch * 64 + hh] + pekw[cch * 64 + ww];
          kv[((long long)(b * 256 + cch)) * 4096 + n] = v;
        }
      }
    }
  }
}

// K3: logitsP[chunk][b,h,c,d] = scale * sum_{n in chunk} q[c,n] k[d,n], 3-term split-bf16
__global__ __launch_bounds__(256) void k_logits(
    const float* __restrict__ out,   // q at [:,0:256]
    const float* __restrict__ kv,    // k
    float* __restrict__ logitsP) {
  int bx = blockIdx.x;
  int chunk = bx & 3, bh = bx >> 2;
  int b = bh >> 3, h = bh & 7;
  int t = threadIdx.x, lane = t & 63, w = t >> 6;
  int l15 = lane & 15, l4 = lane >> 4;
  const float* qb = out + ((long long)(b * 512 + h * 32)) * 4096;
  const float* kb = kv + ((long long)(b * 256 + h * 32)) * 4096;
  f32x4 z = {0.f, 0.f, 0.f, 0.f};
  f32x4 acc[2][2] = {z, z, z, z};
  int nstep0 = chunk * 1024 + w * 256;
  for (int it = 0; it < 8; it++) {
    int n = nstep0 + it * 32 + l4 * 8;
    bf16x8 qh0, ql0, qh1, ql1, kh0, kl0, kh1, kl1;
    cvt8(qb + (long long)l15 * 4096 + n, qh0, ql0);
    cvt8(qb + (long long)(16 + l15) * 4096 + n, qh1, ql1);
    cvt8(kb + (long long)l15 * 4096 + n, kh0, kl0);
    cvt8(kb + (long long)(16 + l15) * 4096 + n, kh1, kl1);
    acc[0][0] = __builtin_amdgcn_mfma_f32_16x16x32_bf16(qh0, kh0, acc[0][0], 0, 0, 0);
    acc[0][0] = __builtin_amdgcn_mfma_f32_16x16x32_bf16(qh0, kl0, acc[0][0], 0, 0, 0);
    acc[0][0] = __builtin_amdgcn_mfma_f32_16x16x32_bf16(ql0, kh0, acc[0][0], 0, 0, 0);
    acc[0][1] = __builtin_amdgcn_mfma_f32_16x16x32_bf16(qh0, kh1, acc[0][1], 0, 0, 0);
    acc[0][1] = __builtin_amdgcn_mfma_f32_16x16x32_bf16(qh0, kl1, acc[0][1], 0, 0, 0);
    acc[0][1] = __builtin_amdgcn_mfma_f32_16x16x32_bf16(ql0, kh1, acc[0][1], 0, 0, 0);
    acc[1][0] = __builtin_amdgcn_mfma_f32_16x16x32_bf16(qh1, kh0, acc[1][0], 0, 0, 0);
    acc[1][0] = __builtin_amdgcn_mfma_f32_16x16x32_bf16(qh1, kl0, acc[1][0], 0, 0, 0);
    acc[1][0] = __builtin_amdgcn_mfma_f32_16x16x32_bf16(ql1, kh0, acc[1][0], 0, 0, 0);
    acc[1][1] = __builtin_amdgcn_mfma_f32_16x16x32_bf16(qh1, kh1, acc[1][1], 0, 0, 0);
    acc[1][1] = __builtin_amdgcn_mfma_f32_16x16x32_bf16(qh1, kl1, acc[1][1], 0, 0, 0);
    acc[1][1] = __builtin_amdgcn_mfma_f32_16x16x32_bf16(ql1, kh1, acc[1][1], 0, 0, 0);
  }
  __shared__ float red[4][1024];
  #pragma unroll
  for (int ch = 0; ch < 2; ch++)
    #pragma unroll
    for (int dh = 0; dh < 2; dh++)
      #pragma unroll
      for (int r = 0; r < 4; r++) {
        int crow = ch * 16 + l4 * 4 + r;
        int dcol = dh * 16 + l15;
        red[w][crow * 32 + dcol] = acc[ch][dh][r];
      }
  __syncthreads();
  const float scale = 0.1767766952966369f;  // 1/sqrt(32)
  #pragma unroll
  for (int i = 0; i < 4; i++) {
    int idx = i * 256 + t;
    float s = (red[0][idx] + red[1][idx] + red[2][idx] + red[3][idx]) * scale;
    logitsP[(long long)chunk * 131072 + bh * 1024 + idx] = s;
  }
}

// K5: softmax (sum 4 partials) + out = weights @ v -> out[:,256:512] fp32
__global__ __launch_bounds__(256) void k_pv(
    const float* __restrict__ kv,    // v
    const float* __restrict__ logitsP,
    float* __restrict__ out) {
  int bx = blockIdx.x;
  int ntile = bx & 15, bh = bx >> 4;
  int b = bh >> 3, h = bh & 7;
  int t = threadIdx.x;
  __shared__ float raw[1024];
  __shared__ float wsm[32][33];
  #pragma unroll
  for (int i = 0; i < 4; i++) {
    int idx = i * 256 + t;
    raw[idx] = logitsP[bh * 1024 + idx] + logitsP[131072 + bh * 1024 + idx]
             + logitsP[262144 + bh * 1024 + idx] + logitsP[393216 + bh * 1024 + idx];
  }
  __syncthreads();
  if (t < 32) {
    float mx = -1e30f;
    for (int d = 0; d < 32; d++) mx = fmaxf(mx, raw[t * 32 + d]);
    float e[32]; float s = 0.f;
    for (int d = 0; d < 32; d++) { e[d] = __expf(raw[t * 32 + d] - mx); s += e[d]; }
    float inv = 1.0f / s;
    for (int d = 0; d < 32; d++) wsm[t][d] = e[d] * inv;
  }
  __syncthreads();
  int rg = t >> 6;          // wave-uniform -> wsm broadcast
  int nl = (t & 63) * 4;
  int n0 = ntile * 256 + nl;
  const float* vb = kv + ((long long)(b * 256 + h * 32)) * 4096 + n0;
  float acc[8][4];
  #pragma unroll
  for (int r = 0; r < 8; r++)
    #pragma unroll
    for (int i = 0; i < 4; i++) acc[r][i] = 0.f;
  for (int d = 0; d < 32; d++) {
    float4 vv = *(const float4*)(vb + (long long)d * 4096);
    #pragma unroll
    for (int r = 0; r < 8; r++) {
      float wv = wsm[rg * 8 + r][d];
      acc[r][0] += wv * vv.x; acc[r][1] += wv * vv.y;
      acc[r][2] += wv * vv.z; acc[r][3] += wv * vv.w;
    }
  }
  #pragma unroll
  for (int r = 0; r < 8; r++) {
    long long oidx = ((long long)(b * 512 + 256 + h * 32 + rg * 8 + r)) * 4096 + n0;
    float4 ov = {acc[r][0], acc[r][1], acc[r][2], acc[r][3]};
    *(float4*)(out + oidx) = ov;
  }
}

extern "C" void kernel_launch(void* const* d_in, const int* in_sizes, int n_in,
                              void* d_out, int out_size, void* d_ws, size_t ws_size,
                              hipStream_t stream) {
  const float* x    = (const float*)d_in[0];
  const float* modm = (const float*)d_in[1];
  const float* modb = (const float*)d_in[2];
  const float* Wq   = (const float*)d_in[3];
  const float* qkvb = (const float*)d_in[4];
  const float* peqh = (const float*)d_in[5];
  const float* peqw = (const float*)d_in[6];
  const float* pekh = (const float*)d_in[7];
  const float* pekw = (const float*)d_in[8];
  const float* pab  = (const float*)d_in[9];
  const float* pqb  = (const float*)d_in[10];
  float* out = (float*)d_out;

  // ws layout (69.2 MB): [0,2MB) logitsP f32[4][128][1024]; [2MB,..) kv f32 [16][256][4096]
  float* logitsP = (float*)d_ws;
  float* kv = (float*)((char*)d_ws + 2097152);

  k_prep<<<16384, 256, 0, stream>>>(x, pab, pqb, out);
  k_qkv<<<2048, 256, 0, stream>>>(Wq, qkvb, peqh, peqw, pekh, pekw, modm, modb, out, kv, 0, 4, 1);
  k_logits<<<512, 256, 0, stream>>>(out, kv, logitsP);
  k_qkv<<<1024, 256, 0, stream>>>(Wq, qkvb, peqh, peqw, pekh, pekw, modm, modb, out, kv, 512, 2, 0);
  k_pv<<<2048, 256, 0, stream>>>(kv, logitsP, out);
  k_act<<<16384, 256, 0, stream>>>(x, pab, out);
}